// Round 4
// baseline (135.028 us; speedup 1.0000x reference)
//
#include <hip/hip_runtime.h>
#include <stdint.h>

// ModulatedConv2D: B=8, IC=OC=512, K=3, H=W=32
// 3 dispatches: style (sm, sm2), prep (Wtf repack + dpart demod partials +
// xsp repack), conv (implicit GEMM, 32x32x16 f16 MFMA).
//
// R4 change: R3 (LDS-staged A) halved A L2-traffic but conv stayed ~45us,
// MfmaUtil 33% -- the 2-phase barrier drain stall (m233-class) with only
// 2 waves/SIMD resident (4-wave blocks, 2 blocks/CU) has nothing to overlap
// with. Fix: split oc -> 32oc x 128px blocks, grid 1024 (16,8,8), LDS 32KB
// per block -> 4 blocks/CU = 4 waves/SIMD; four independent barrier groups
// per CU overlap each other's drains (m114/m97 mechanism). Per-XCD weight
// locality preserved (blockIdx.x&7 = weight slice). Staging has fixed
// per-wave g2l counts {5,4,4,4} (counted-vmcnt-ready).

#define B_   8
#define IC_  512
#define OC_  512

static constexpr float RC_DENSE = 0.04419417382415922f;   // 1/sqrt(512)
static constexpr float RC_CONV  = 0.014731391274719739f;  // 1/sqrt(4608)

typedef _Float16 half8    __attribute__((ext_vector_type(8)));
typedef float    floatx16 __attribute__((ext_vector_type(16)));

// async global->LDS, 16B per lane; LDS dest = wave-uniform base + lane*16
__device__ __forceinline__ void g2l(const void* g, void* l) {
  __builtin_amdgcn_global_load_lds(
      (const __attribute__((address_space(1))) void*)g,
      (__attribute__((address_space(3))) void*)l, 16, 0, 0);
}

// ---- sm = (w@(RC_DENSE*dw) + db + 1)*RC_CONV ; sm2 = sm^2 ----
__global__ __launch_bounds__(256) void style_kernel(
    const float* __restrict__ wv, const float* __restrict__ dw,
    const float* __restrict__ db, float* __restrict__ sm,
    float* __restrict__ sm2) {
  const int b = blockIdx.y;
  const int i = blockIdx.x * 64 + (threadIdx.x & 63);
  const int jg = threadIdx.x >> 6;
  __shared__ float red[4][64];
  float p = 0.f;
  for (int j = jg * 128; j < jg * 128 + 128; ++j)
    p += wv[b * IC_ + j] * dw[(size_t)j * IC_ + i];
  red[jg][threadIdx.x & 63] = p;
  __syncthreads();
  if (threadIdx.x < 64) {
    float s = red[0][threadIdx.x] + red[1][threadIdx.x] +
              red[2][threadIdx.x] + red[3][threadIdx.x];
    s = s * RC_DENSE + db[i] + 1.0f;
    float v = s * RC_CONV;
    sm[b * IC_ + i] = v;
    sm2[b * IC_ + i] = v * v;
  }
}

// ---------------- prep: 512 blocks (2/CU) ----------------
// bid<256 (wts role): 32oc x 32ic half-tile; Wtf[by][icb][ktq 36][oc64][8] f16
//   + dpart[icb][b][oc] = sum_icl sm2 * sum_t cw^2 (disjoint oc, no atomics)
// bid>=256 (xsp role): per (b,h) row; xsp[b][icb][r34][kk2][kq2][C34][8] f16
__global__ __launch_bounds__(256) void prep_kernel(
    const float* __restrict__ cw, const float* __restrict__ x,
    const float* __restrict__ sm, const float* __restrict__ sm2,
    _Float16* __restrict__ Wtf, float* __restrict__ dpart,
    _Float16* __restrict__ xsp) {
  __shared__ __align__(16) char smem[33280];
  const int bid = blockIdx.x;
  const int tid = threadIdx.x;
  if (bid < 256) {
    // ---------------- wts + dpart role ----------------
    _Float16* LA = (_Float16*)smem;                // 18432 B
    float* redall = (float*)(smem + 18432);        // 8192 B (8b x 8g x 32oc)
    const int by2 = bid >> 4, icb = bid & 15;
    const int by = by2 >> 1, h2 = by2 & 1;
    const int oc0 = by * 64 + h2 * 32, ic0 = icb * 32;
    const int ocl = tid & 31, g = tid >> 5;        // g 0..7
    float sq4[4] = {};
    for (int m = 0; m < 36; ++m) {
      int r = m * 8 + g;                 // r = t*32+icl; t=m>>2, icl=8*(m&3)+g
      int t = r >> 5, icl = r & 31;
      float v = cw[(size_t)(t * IC_ + ic0 + icl) * OC_ + oc0 + ocl];  // 128B seg
      sq4[m & 3] += v * v;
      LA[m * 256 + ocl * 8 + g] = (_Float16)v;     // ktq == m, j == g
    }
    for (int b = 0; b < 8; ++b) {
      float p = 0.f;
      for (int s = 0; s < 4; ++s)
        p += sm2[b * IC_ + ic0 + g + 8 * s] * sq4[s];
      redall[(b * 8 + g) * 32 + ocl] = p;
    }
    __syncthreads();
    // Wtf: 1152 contiguous-per-wave b128 chunks
    _Float16* dst = Wtf + (size_t)(by * 16 + icb) * 18432;
    for (int it = 0; it < 5; ++it) {
      int c = it * 256 + tid;
      if (c < 1152) {
        int m = c >> 5, o2 = c & 31;
        *(half8*)(dst + (size_t)(m * 64 + h2 * 32 + o2) * 8) =
            *(const half8*)&LA[m * 256 + o2 * 8];
      }
    }
    // dpart: reduce over g
    const int bb = tid >> 5, o3 = tid & 31;
    float s = 0.f;
    for (int g2 = 0; g2 < 8; ++g2) s += redall[(bb * 8 + g2) * 32 + o3];
    dpart[(size_t)icb * 4096 + bb * OC_ + oc0 + o3] = s;
  } else {
    // ---------------- xsp role (R4-proven structure) ----------------
    _Float16* Xt = (_Float16*)smem;                // 32*520*2 = 33280 B
    const int rb = bid - 256;
    const int b = rb >> 5, h = rb & 31;
    for (int k = 0; k < 16; ++k) {
      int idx = k * 256 + tid;           // 512 ic * 8 w-quads
      int ic = idx >> 3, wc = (idx & 7) * 4;
      float4 v = *(const float4*)&x[((size_t)(b * IC_ + ic) * 32 + h) * 32 + wc];
      float s = sm[b * IC_ + ic];
      Xt[(wc + 0) * 520 + ic] = (_Float16)(v.x * s);
      Xt[(wc + 1) * 520 + ic] = (_Float16)(v.y * s);
      Xt[(wc + 2) * 520 + ic] = (_Float16)(v.z * s);
      Xt[(wc + 3) * 520 + ic] = (_Float16)(v.w * s);
    }
    __syncthreads();
    _Float16* xb = xsp + (size_t)b * 16 * 36992;
    const int r = h + 1;
    half8 z = {};
    for (int it = 0; it < 9; ++it) {     // 16 icb * 4 kkq * 34 C = 2176 chunks
      int c = it * 256 + tid;
      if (c < 2176) {
        int icb = c / 136, rem = c - 136 * icb, kkq = rem / 34, C = rem - 34 * kkq;
        half8 val = z;
        if (C != 0 && C != 33)
          val = *(const half8*)&Xt[(C - 1) * 520 + icb * 32 + kkq * 8];
        *(half8*)&xb[(size_t)icb * 36992 + (size_t)r * 1088 + kkq * 272 + C * 8] = val;
      }
    }
    if (h == 0 || h == 31) {             // zero top/bottom padded rows
      const int rz = (h == 0) ? 0 : 33;
      for (int it = 0; it < 9; ++it) {
        int c = it * 256 + tid;
        if (c < 2176) {
          int icb = c / 136, rem = c - 136 * icb, kkq = rem / 34, C = rem - 34 * kkq;
          *(half8*)&xb[(size_t)icb * 36992 + (size_t)rz * 1088 + kkq * 272 + C * 8] = z;
        }
      }
    }
  }
}

// ---- conv: block 32oc x 128px (4 rows), grid (x 16, bx 8, b 8) = 1024 ----
// blockIdx.x = byq + 8*hoc: byq = weight 64-oc slice (== XCD via linear%8),
// hoc = which 32-oc half. 4 waves/block, wave w owns output row h0+w
// (one 32x32 tile, acc x16). K-loop: 32 sub-steps (icb x kk), A-quarter
// (9216 B) + X-half (6528 B) staged via global_load_lds, double-buffered;
// LDS = 32 KB/block -> 4 blocks/CU (16 waves/CU). Per-wave g2l counts are
// fixed {5,4,4,4} (A: w0 gets 3 instrs, others 2; X: 2 each, 2nd partial).
__global__ __launch_bounds__(256, 4) void conv_kernel(
    const _Float16* __restrict__ Wtf,   // [8 byq][16 icb][36 m][64 oc][8]
    const _Float16* __restrict__ xsp,   // [8 b][16 icb][34 r][2 kk][2 kq][34 C][8]
    const float* __restrict__ dpart,    // [16 icb][8 b][512 oc]
    float* __restrict__ out) {          // [8][512][32][32]
  const int byq = blockIdx.x & 7, hoc = blockIdx.x >> 3;
  const int bx = blockIdx.y, b = blockIdx.z;
  const int tid = threadIdx.x, lane = tid & 63, w = tid >> 6;  // w: out row
  const int n = lane & 31, kq = lane >> 5;
  const int h0 = bx * 4;                // output rows h0..h0+3; padded h0..h0+5

  __shared__ __align__(16) _Float16 As[2][4608];   // 9216 B each
  __shared__ __align__(16) _Float16 Xs[2][3264];   // 6528 B each
  __shared__ float redd[8][32];
  __shared__ float dvl[32];

  const _Float16* gX = xsp + (size_t)b * 16 * 36992 + (size_t)h0 * 1088;
  const _Float16* gA = Wtf + (size_t)byq * 16 * 18432 + hoc * 256;

  // A chunks: c in [0,576): r=c>>5 (0..17), o2=c&31;
  //   src halfs = icb*18432 + ((r>>1)*4 + kk*2 + (r&1))*512 + hoc*256 + o2*8
  //   wave-instr split: w0 instrs {0,1,2}, w1 {3,4}, w2 {5,6}, w3 {7,8}
  // X chunks: c in [0,408): r=c/68, o=c%68;
  //   src halfs = icb*36992 + kk*544 + r*1088 + o*8
  //   wave w covers [w*102, w*102+102): full instr + 38-lane partial
  const int nA = (w == 0) ? 3 : 2;
  const int iA = (w == 0) ? 0 : 1 + 2 * w;      // w0:0 w1:3 w2:5 w3:7

  auto stage = [&](int st, int p) {
    const int icb = st >> 1, kk = st & 1;
    const _Float16* a = gA + (size_t)icb * 18432 + kk * 1024;
    for (int k = 0; k < nA; ++k) {
      int c = (iA + k) * 64 + lane;
      int r = c >> 5, o2 = c & 31;
      g2l(a + ((r >> 1) * 4 + (r & 1)) * 512 + o2 * 8, &As[p][c * 8]);
    }
    const _Float16* xg = gX + (size_t)icb * 36992 + kk * 544;
    {
      int c = w * 102 + lane;
      int r = c / 68, o = c - r * 68;
      g2l(xg + r * 1088 + o * 8, &Xs[p][c * 8]);
      c += 64;
      if (lane < 38) {
        int r2 = c / 68, o2x = c - r2 * 68;
        g2l(xg + r2 * 1088 + o2x * 8, &Xs[p][c * 8]);
      }
    }
  };

  floatx16 acc = {};
  stage(0, 0);
  for (int st = 0; st < 32; ++st) {
    const int cur = st & 1;
    __syncthreads();                    // buf[cur] staged & visible
    if (st + 1 < 32) stage(st + 1, cur ^ 1);
    const _Float16* Ap = &As[cur][0] + kq * 256 + n * 8;
    const _Float16* Xp = &Xs[cur][0] + w * 544 + kq * 272 + n * 8;
    half8 a[9];
#pragma unroll
    for (int t = 0; t < 9; ++t) a[t] = *(const half8*)(Ap + t * 512);
#pragma unroll
    for (int s = 0; s < 3; ++s) {       // kh == s for this wave's single row
#pragma unroll
      for (int kw = 0; kw < 3; ++kw) {
        half8 xv = *(const half8*)(Xp + s * 544 + kw * 8);
        acc = __builtin_amdgcn_mfma_f32_32x32x16_f16(a[s * 3 + kw], xv, acc,
                                                     0, 0, 0);
      }
    }
  }

  // epilogue: reduce dpart over 16 icb -> dvl[32], then plain stores
  const int oc0 = byq * 64 + hoc * 32;
  __syncthreads();
  {
    const int oc_l = tid & 31, ig = tid >> 5;
    float s = dpart[(size_t)(ig * 2) * 4096 + b * OC_ + oc0 + oc_l] +
              dpart[(size_t)(ig * 2 + 1) * 4096 + b * OC_ + oc0 + oc_l];
    redd[ig][oc_l] = s;
  }
  __syncthreads();
  if (tid < 32) {
    float s = 1e-8f;
#pragma unroll
    for (int g = 0; g < 8; ++g) s += redd[g][tid];
    dvl[tid] = rsqrtf(s);
  }
  __syncthreads();
  // D col(px)=n, row(oc within 32)=(rg&3)+8*(rg>>2)+4*kq
#pragma unroll
  for (int rg = 0; rg < 16; ++rg) {
    const int row = (rg & 3) + 8 * (rg >> 2) + 4 * kq;
    float* op = out + ((size_t)b * OC_ + oc0 + row) * 1024 + (h0 + w) * 32 + n;
    op[0] = acc[rg] * dvl[row];
  }
}

extern "C" void kernel_launch(void* const* d_in, const int* in_sizes, int n_in,
                              void* d_out, int out_size, void* d_ws, size_t ws_size,
                              hipStream_t stream) {
  const float* x       = (const float*)d_in[0];
  const float* w       = (const float*)d_in[1];
  const float* conv_w  = (const float*)d_in[2];
  const float* dense_w = (const float*)d_in[3];
  const float* dense_b = (const float*)d_in[4];
  float* out = (float*)d_out;

  char* ws = (char*)d_ws;
  float*    sm    = (float*)ws;                        // 16 KB
  float*    sm2   = (float*)(ws + (16 << 10));         // 16 KB
  float*    dpart = (float*)(ws + (32 << 10));         // 256 KB
  _Float16* Wtf   = (_Float16*)(ws + (288 << 10));               // 4,718,592 B
  _Float16* xsp   = (_Float16*)(ws + (288 << 10) + 4718592);     // 9,469,952 B

  style_kernel<<<dim3(8, B_), 256, 0, stream>>>(w, dense_w, dense_b, sm, sm2);
  prep_kernel<<<512, 256, 0, stream>>>(conv_w, x, sm, sm2, Wtf, dpart, xsp);
  conv_kernel<<<dim3(16, 8, B_), 256, 0, stream>>>(Wtf, xsp, dpart, out);
}

// Round 5
// 132.852 us; speedup vs baseline: 1.0164x; 1.0164x over previous
//
#include <hip/hip_runtime.h>
#include <stdint.h>

// ModulatedConv2D: B=8, IC=OC=512, K=3, H=W=32
// 3 dispatches: style (sm, sm2), prep (Wtf repack + dpart demod partials +
// xsp repack), conv (implicit GEMM, 32x32x16 f16 MFMA).
//
// R5 change: R0-R4 all sat at MfmaUtil ~33% regardless of staging scheme or
// occupancy -- the common factor is __syncthreads()'s mandatory
// s_waitcnt vmcnt(0) drain per sub-step (the m233 2-phase stall). Fix
// (T3+T4): raw s_barrier + counted vmcnt. Staging is rebalanced so EVERY
// wave issues exactly 4 global_load_lds per stage; in steady state each
// wave issues the next stage's 4 loads, then waits vmcnt(4) (its previous
// buffer's writes done, next buffer's 4 still in flight ACROSS the
// barrier), s_barrier, MFMA cluster, s_barrier. vmcnt never drains to 0
// in the main loop (AITER pattern). sched_barrier(0) pins both sides.

#define B_   8
#define IC_  512
#define OC_  512

static constexpr float RC_DENSE = 0.04419417382415922f;   // 1/sqrt(512)
static constexpr float RC_CONV  = 0.014731391274719739f;  // 1/sqrt(4608)

typedef _Float16 half8    __attribute__((ext_vector_type(8)));
typedef float    floatx16 __attribute__((ext_vector_type(16)));

// async global->LDS, 16B per lane; LDS dest = wave-uniform base + lane*16
__device__ __forceinline__ void g2l(const void* g, void* l) {
  __builtin_amdgcn_global_load_lds(
      (const __attribute__((address_space(1))) void*)g,
      (__attribute__((address_space(3))) void*)l, 16, 0, 0);
}

// ---- sm = (w@(RC_DENSE*dw) + db + 1)*RC_CONV ; sm2 = sm^2 ----
__global__ __launch_bounds__(256) void style_kernel(
    const float* __restrict__ wv, const float* __restrict__ dw,
    const float* __restrict__ db, float* __restrict__ sm,
    float* __restrict__ sm2) {
  const int b = blockIdx.y;
  const int i = blockIdx.x * 64 + (threadIdx.x & 63);
  const int jg = threadIdx.x >> 6;
  __shared__ float red[4][64];
  float p = 0.f;
  for (int j = jg * 128; j < jg * 128 + 128; ++j)
    p += wv[b * IC_ + j] * dw[(size_t)j * IC_ + i];
  red[jg][threadIdx.x & 63] = p;
  __syncthreads();
  if (threadIdx.x < 64) {
    float s = red[0][threadIdx.x] + red[1][threadIdx.x] +
              red[2][threadIdx.x] + red[3][threadIdx.x];
    s = s * RC_DENSE + db[i] + 1.0f;
    float v = s * RC_CONV;
    sm[b * IC_ + i] = v;
    sm2[b * IC_ + i] = v * v;
  }
}

// ---------------- prep: 512 blocks (2/CU) ----------------
// bid<256 (wts role): 32oc x 32ic half-tile; Wtf[by][icb][ktq 36][oc64][8] f16
//   + dpart[icb][b][oc] = sum_icl sm2 * sum_t cw^2 (disjoint oc, no atomics)
// bid>=256 (xsp role): per (b,h) row; xsp[b][icb][r34][kk2][kq2][C34][8] f16
__global__ __launch_bounds__(256) void prep_kernel(
    const float* __restrict__ cw, const float* __restrict__ x,
    const float* __restrict__ sm, const float* __restrict__ sm2,
    _Float16* __restrict__ Wtf, float* __restrict__ dpart,
    _Float16* __restrict__ xsp) {
  __shared__ __align__(16) char smem[33280];
  const int bid = blockIdx.x;
  const int tid = threadIdx.x;
  if (bid < 256) {
    // ---------------- wts + dpart role ----------------
    _Float16* LA = (_Float16*)smem;                // 18432 B
    float* redall = (float*)(smem + 18432);        // 8192 B (8b x 8g x 32oc)
    const int by2 = bid >> 4, icb = bid & 15;
    const int by = by2 >> 1, h2 = by2 & 1;
    const int oc0 = by * 64 + h2 * 32, ic0 = icb * 32;
    const int ocl = tid & 31, g = tid >> 5;        // g 0..7
    float sq4[4] = {};
    for (int m = 0; m < 36; ++m) {
      int r = m * 8 + g;                 // r = t*32+icl; t=m>>2, icl=8*(m&3)+g
      int t = r >> 5, icl = r & 31;
      float v = cw[(size_t)(t * IC_ + ic0 + icl) * OC_ + oc0 + ocl];  // 128B seg
      sq4[m & 3] += v * v;
      LA[m * 256 + ocl * 8 + g] = (_Float16)v;     // ktq == m, j == g
    }
    for (int b = 0; b < 8; ++b) {
      float p = 0.f;
      for (int s = 0; s < 4; ++s)
        p += sm2[b * IC_ + ic0 + g + 8 * s] * sq4[s];
      redall[(b * 8 + g) * 32 + ocl] = p;
    }
    __syncthreads();
    // Wtf: 1152 contiguous-per-wave b128 chunks
    _Float16* dst = Wtf + (size_t)(by * 16 + icb) * 18432;
    for (int it = 0; it < 5; ++it) {
      int c = it * 256 + tid;
      if (c < 1152) {
        int m = c >> 5, o2 = c & 31;
        *(half8*)(dst + (size_t)(m * 64 + h2 * 32 + o2) * 8) =
            *(const half8*)&LA[m * 256 + o2 * 8];
      }
    }
    // dpart: reduce over g
    const int bb = tid >> 5, o3 = tid & 31;
    float s = 0.f;
    for (int g2 = 0; g2 < 8; ++g2) s += redall[(bb * 8 + g2) * 32 + o3];
    dpart[(size_t)icb * 4096 + bb * OC_ + oc0 + o3] = s;
  } else {
    // ---------------- xsp role (R4-proven structure) ----------------
    _Float16* Xt = (_Float16*)smem;                // 32*520*2 = 33280 B
    const int rb = bid - 256;
    const int b = rb >> 5, h = rb & 31;
    for (int k = 0; k < 16; ++k) {
      int idx = k * 256 + tid;           // 512 ic * 8 w-quads
      int ic = idx >> 3, wc = (idx & 7) * 4;
      float4 v = *(const float4*)&x[((size_t)(b * IC_ + ic) * 32 + h) * 32 + wc];
      float s = sm[b * IC_ + ic];
      Xt[(wc + 0) * 520 + ic] = (_Float16)(v.x * s);
      Xt[(wc + 1) * 520 + ic] = (_Float16)(v.y * s);
      Xt[(wc + 2) * 520 + ic] = (_Float16)(v.z * s);
      Xt[(wc + 3) * 520 + ic] = (_Float16)(v.w * s);
    }
    __syncthreads();
    _Float16* xb = xsp + (size_t)b * 16 * 36992;
    const int r = h + 1;
    half8 z = {};
    for (int it = 0; it < 9; ++it) {     // 16 icb * 4 kkq * 34 C = 2176 chunks
      int c = it * 256 + tid;
      if (c < 2176) {
        int icb = c / 136, rem = c - 136 * icb, kkq = rem / 34, C = rem - 34 * kkq;
        half8 val = z;
        if (C != 0 && C != 33)
          val = *(const half8*)&Xt[(C - 1) * 520 + icb * 32 + kkq * 8];
        *(half8*)&xb[(size_t)icb * 36992 + (size_t)r * 1088 + kkq * 272 + C * 8] = val;
      }
    }
    if (h == 0 || h == 31) {             // zero top/bottom padded rows
      const int rz = (h == 0) ? 0 : 33;
      for (int it = 0; it < 9; ++it) {
        int c = it * 256 + tid;
        if (c < 2176) {
          int icb = c / 136, rem = c - 136 * icb, kkq = rem / 34, C = rem - 34 * kkq;
          *(half8*)&xb[(size_t)icb * 36992 + (size_t)rz * 1088 + kkq * 272 + C * 8] = z;
        }
      }
    }
  }
}

// ---- conv: block 32oc x 128px (4 rows), grid (x 16, bx 8, b 8) = 1024 ----
// blockIdx.x = byq + 8*hoc; XCD = linear%8 = byq (weight slice locality).
// 4 waves/block, wave w owns output row h0+w (one 32x32 tile, acc x16).
// 32 sub-steps (icb x kk); A-quarter (9216 B) + X-half (6528 B) per stage,
// double-buffered (LDS 32 KB -> 4 blocks/CU). Staging split into 16
// wave-uniform 64-chunk g2l groups, exactly 4 PER WAVE (A groups 0-8:
// w0 0-3, w1 4-7, w2 {8}; X groups 0-6: w2 0-2, w3 3-6 last partial), so
// s_waitcnt vmcnt(4) is per-wave exact. Counted-vmcnt pipeline: loads for
// buf[next] stay in flight across both barriers of the current sub-step.
__global__ __launch_bounds__(256, 4) void conv_kernel(
    const _Float16* __restrict__ Wtf,   // [8 byq][16 icb][36 m][64 oc][8]
    const _Float16* __restrict__ xsp,   // [8 b][16 icb][34 r][2 kk][2 kq][34 C][8]
    const float* __restrict__ dpart,    // [16 icb][8 b][512 oc]
    float* __restrict__ out) {          // [8][512][32][32]
  const int byq = blockIdx.x & 7, hoc = blockIdx.x >> 3;
  const int bx = blockIdx.y, b = blockIdx.z;
  const int tid = threadIdx.x, lane = tid & 63, w = tid >> 6;  // w: out row
  const int n = lane & 31, kq = lane >> 5;
  const int h0 = bx * 4;                // output rows h0..h0+3; padded h0..h0+5

  __shared__ __align__(16) _Float16 As[2][4608];   // 9216 B each
  __shared__ __align__(16) _Float16 Xs[2][3264];   // 6528 B each
  __shared__ float redd[8][32];
  __shared__ float dvl[32];

  const _Float16* gX = xsp + (size_t)b * 16 * 36992 + (size_t)h0 * 1088;
  const _Float16* gA = Wtf + (size_t)byq * 16 * 18432 + hoc * 256;

  // A chunks c in [0,576): r=c>>5 (0..17), o2=c&31;
  //   src halfs = icb*18432 + ((r>>1)*4 + kk*2 + (r&1))*512 + hoc*256 + o2*8
  // X chunks c in [0,408): r=c/68, o=c%68;
  //   src halfs = icb*36992 + kk*544 + r*1088 + o*8
  // 64-chunk groups: A 0-8 (9), X 0-6 (7, last 24 lanes). 4 g2l per wave.
  auto stage = [&](int st, int p) {
    const int icb = st >> 1, kk = st & 1;
    const _Float16* a = gA + (size_t)icb * 18432 + kk * 1024;
    const _Float16* xg = gX + (size_t)icb * 36992 + kk * 544;
    if (w < 2) {
#pragma unroll
      for (int k = 0; k < 4; ++k) {      // A groups 4w..4w+3
        int c = (w * 4 + k) * 64 + lane;
        int r = c >> 5, o2 = c & 31;
        g2l(a + ((r >> 1) * 4 + (r & 1)) * 512 + o2 * 8, &As[p][c * 8]);
      }
    } else if (w == 2) {
      {                                  // A group 8
        int c = 8 * 64 + lane;
        int r = c >> 5, o2 = c & 31;
        g2l(a + ((r >> 1) * 4 + (r & 1)) * 512 + o2 * 8, &As[p][c * 8]);
      }
#pragma unroll
      for (int k = 0; k < 3; ++k) {      // X groups 0-2
        int c = k * 64 + lane;
        int r = c / 68, o = c - r * 68;
        g2l(xg + r * 1088 + o * 8, &Xs[p][c * 8]);
      }
    } else {
#pragma unroll
      for (int k = 0; k < 3; ++k) {      // X groups 3-5
        int c = (3 + k) * 64 + lane;
        int r = c / 68, o = c - r * 68;
        g2l(xg + r * 1088 + o * 8, &Xs[p][c * 8]);
      }
      {                                  // X group 6 (partial: 24 lanes)
        int c = 6 * 64 + lane;
        if (lane < 24) {
          int r = c / 68, o = c - r * 68;
          g2l(xg + r * 1088 + o * 8, &Xs[p][c * 8]);
        }
      }
    }
  };

  floatx16 acc = {};
  stage(0, 0);                           // prologue: 4 g2l in flight
  for (int st = 0; st < 32; ++st) {
    const int cur = st & 1;
    if (st + 1 < 32) {
      stage(st + 1, cur ^ 1);            // issue next (4 g2l) -> 8 in flight
      asm volatile("s_waitcnt vmcnt(4)" ::: "memory");  // my buf[cur] done
    } else {
      asm volatile("s_waitcnt vmcnt(0)" ::: "memory");
    }
    __builtin_amdgcn_s_barrier();        // all waves' buf[cur] writes done
    __builtin_amdgcn_sched_barrier(0);   // pin: no ds_read hoists above
    const _Float16* Ap = &As[cur][0] + kq * 256 + n * 8;
    const _Float16* Xp = &Xs[cur][0] + w * 544 + kq * 272 + n * 8;
    half8 a[9];
#pragma unroll
    for (int t = 0; t < 9; ++t) a[t] = *(const half8*)(Ap + t * 512);
#pragma unroll
    for (int s = 0; s < 3; ++s) {        // kh == s for this wave's single row
#pragma unroll
      for (int kw = 0; kw < 3; ++kw) {
        half8 xv = *(const half8*)(Xp + s * 544 + kw * 8);
        acc = __builtin_amdgcn_mfma_f32_32x32x16_f16(a[s * 3 + kw], xv, acc,
                                                     0, 0, 0);
      }
    }
    __builtin_amdgcn_sched_barrier(0);   // pin: no ds_read sinks below
    __builtin_amdgcn_s_barrier();        // buf[cur^1] reads done (WAR for next stage)
  }

  // epilogue: reduce dpart over 16 icb -> dvl[32], then plain stores
  const int oc0 = byq * 64 + hoc * 32;
  __syncthreads();
  {
    const int oc_l = tid & 31, ig = tid >> 5;
    float s = dpart[(size_t)(ig * 2) * 4096 + b * OC_ + oc0 + oc_l] +
              dpart[(size_t)(ig * 2 + 1) * 4096 + b * OC_ + oc0 + oc_l];
    redd[ig][oc_l] = s;
  }
  __syncthreads();
  if (tid < 32) {
    float s = 1e-8f;
#pragma unroll
    for (int g = 0; g < 8; ++g) s += redd[g][tid];
    dvl[tid] = rsqrtf(s);
  }
  __syncthreads();
  // D col(px)=n, row(oc within 32)=(rg&3)+8*(rg>>2)+4*kq
#pragma unroll
  for (int rg = 0; rg < 16; ++rg) {
    const int row = (rg & 3) + 8 * (rg >> 2) + 4 * kq;
    float* op = out + ((size_t)b * OC_ + oc0 + row) * 1024 + (h0 + w) * 32 + n;
    op[0] = acc[rg] * dvl[row];
  }
}

extern "C" void kernel_launch(void* const* d_in, const int* in_sizes, int n_in,
                              void* d_out, int out_size, void* d_ws, size_t ws_size,
                              hipStream_t stream) {
  const float* x       = (const float*)d_in[0];
  const float* w       = (const float*)d_in[1];
  const float* conv_w  = (const float*)d_in[2];
  const float* dense_w = (const float*)d_in[3];
  const float* dense_b = (const float*)d_in[4];
  float* out = (float*)d_out;

  char* ws = (char*)d_ws;
  float*    sm    = (float*)ws;                        // 16 KB
  float*    sm2   = (float*)(ws + (16 << 10));         // 16 KB
  float*    dpart = (float*)(ws + (32 << 10));         // 256 KB
  _Float16* Wtf   = (_Float16*)(ws + (288 << 10));               // 4,718,592 B
  _Float16* xsp   = (_Float16*)(ws + (288 << 10) + 4718592);     // 9,469,952 B

  style_kernel<<<dim3(8, B_), 256, 0, stream>>>(w, dense_w, dense_b, sm, sm2);
  prep_kernel<<<512, 256, 0, stream>>>(conv_w, x, sm, sm2, Wtf, dpart, xsp);
  conv_kernel<<<dim3(16, 8, B_), 256, 0, stream>>>(Wtf, xsp, dpart, out);
}

// Round 6
// 127.877 us; speedup vs baseline: 1.0559x; 1.0389x over previous
//
#include <hip/hip_runtime.h>
#include <stdint.h>

// ModulatedConv2D: B=8, IC=OC=512, K=3, H=W=32
// 3 dispatches: style (sm, sm2), prep (Wtf repack + dpart demod partials +
// xsp repack), conv (implicit GEMM, 32x32x16 f16 MFMA).
//
// R6 change: R0-R5 all pinned at MfmaUtil~33%. Invariant found: LDS READ
// PORT. R5 = 288 ds_read_b128/CU/sub-step x 12cyc = 3456cyc == observed
// 3528cyc sub-step (MFMA only 1152). 4 waves/block redundantly read the
// same A frags; 1-row waves give no X reuse (0.5 MFMA/read). Fix: wave
// tile 32oc x 64px (2 rows, acc[2]) -> 18 MFMA per 21 reads; 8 waves/CU
// (2 blocks of 4 waves). LDS cycles/CU/sub-step 3456 -> 2016. R5's
// counted-vmcnt skeleton kept (5 g2l/wave -> vmcnt(5)); setprio around
// MFMA cluster (T5, role diversity now exists).

#define B_   8
#define IC_  512
#define OC_  512

static constexpr float RC_DENSE = 0.04419417382415922f;   // 1/sqrt(512)
static constexpr float RC_CONV  = 0.014731391274719739f;  // 1/sqrt(4608)

typedef _Float16 half8    __attribute__((ext_vector_type(8)));
typedef float    floatx16 __attribute__((ext_vector_type(16)));

// async global->LDS, 16B per lane; LDS dest = wave-uniform base + lane*16
__device__ __forceinline__ void g2l(const void* g, void* l) {
  __builtin_amdgcn_global_load_lds(
      (const __attribute__((address_space(1))) void*)g,
      (__attribute__((address_space(3))) void*)l, 16, 0, 0);
}

// ---- sm = (w@(RC_DENSE*dw) + db + 1)*RC_CONV ; sm2 = sm^2 ----
__global__ __launch_bounds__(256) void style_kernel(
    const float* __restrict__ wv, const float* __restrict__ dw,
    const float* __restrict__ db, float* __restrict__ sm,
    float* __restrict__ sm2) {
  const int b = blockIdx.y;
  const int i = blockIdx.x * 64 + (threadIdx.x & 63);
  const int jg = threadIdx.x >> 6;
  __shared__ float red[4][64];
  float p = 0.f;
  for (int j = jg * 128; j < jg * 128 + 128; ++j)
    p += wv[b * IC_ + j] * dw[(size_t)j * IC_ + i];
  red[jg][threadIdx.x & 63] = p;
  __syncthreads();
  if (threadIdx.x < 64) {
    float s = red[0][threadIdx.x] + red[1][threadIdx.x] +
              red[2][threadIdx.x] + red[3][threadIdx.x];
    s = s * RC_DENSE + db[i] + 1.0f;
    float v = s * RC_CONV;
    sm[b * IC_ + i] = v;
    sm2[b * IC_ + i] = v * v;
  }
}

// ---------------- prep: 512 blocks (2/CU) ----------------
// bid<256 (wts role): 32oc x 32ic half-tile; Wtf[by][icb][ktq 36][oc64][8] f16
//   + dpart[icb][b][oc] = sum_icl sm2 * sum_t cw^2 (disjoint oc, no atomics)
// bid>=256 (xsp role): per (b,h) row; xsp[b][icb][r34][kk2][kq2][C34][8] f16
__global__ __launch_bounds__(256) void prep_kernel(
    const float* __restrict__ cw, const float* __restrict__ x,
    const float* __restrict__ sm, const float* __restrict__ sm2,
    _Float16* __restrict__ Wtf, float* __restrict__ dpart,
    _Float16* __restrict__ xsp) {
  __shared__ __align__(16) char smem[33280];
  const int bid = blockIdx.x;
  const int tid = threadIdx.x;
  if (bid < 256) {
    // ---------------- wts + dpart role ----------------
    _Float16* LA = (_Float16*)smem;                // 18432 B
    float* redall = (float*)(smem + 18432);        // 8192 B (8b x 8g x 32oc)
    const int by2 = bid >> 4, icb = bid & 15;
    const int by = by2 >> 1, h2 = by2 & 1;
    const int oc0 = by * 64 + h2 * 32, ic0 = icb * 32;
    const int ocl = tid & 31, g = tid >> 5;        // g 0..7
    float sq4[4] = {};
    for (int m = 0; m < 36; ++m) {
      int r = m * 8 + g;                 // r = t*32+icl; t=m>>2, icl=8*(m&3)+g
      int t = r >> 5, icl = r & 31;
      float v = cw[(size_t)(t * IC_ + ic0 + icl) * OC_ + oc0 + ocl];  // 128B seg
      sq4[m & 3] += v * v;
      LA[m * 256 + ocl * 8 + g] = (_Float16)v;     // ktq == m, j == g
    }
    for (int b = 0; b < 8; ++b) {
      float p = 0.f;
      for (int s = 0; s < 4; ++s)
        p += sm2[b * IC_ + ic0 + g + 8 * s] * sq4[s];
      redall[(b * 8 + g) * 32 + ocl] = p;
    }
    __syncthreads();
    // Wtf: 1152 contiguous-per-wave b128 chunks
    _Float16* dst = Wtf + (size_t)(by * 16 + icb) * 18432;
    for (int it = 0; it < 5; ++it) {
      int c = it * 256 + tid;
      if (c < 1152) {
        int m = c >> 5, o2 = c & 31;
        *(half8*)(dst + (size_t)(m * 64 + h2 * 32 + o2) * 8) =
            *(const half8*)&LA[m * 256 + o2 * 8];
      }
    }
    // dpart: reduce over g
    const int bb = tid >> 5, o3 = tid & 31;
    float s = 0.f;
    for (int g2 = 0; g2 < 8; ++g2) s += redall[(bb * 8 + g2) * 32 + o3];
    dpart[(size_t)icb * 4096 + bb * OC_ + oc0 + o3] = s;
  } else {
    // ---------------- xsp role (R4-proven structure) ----------------
    _Float16* Xt = (_Float16*)smem;                // 32*520*2 = 33280 B
    const int rb = bid - 256;
    const int b = rb >> 5, h = rb & 31;
    for (int k = 0; k < 16; ++k) {
      int idx = k * 256 + tid;           // 512 ic * 8 w-quads
      int ic = idx >> 3, wc = (idx & 7) * 4;
      float4 v = *(const float4*)&x[((size_t)(b * IC_ + ic) * 32 + h) * 32 + wc];
      float s = sm[b * IC_ + ic];
      Xt[(wc + 0) * 520 + ic] = (_Float16)(v.x * s);
      Xt[(wc + 1) * 520 + ic] = (_Float16)(v.y * s);
      Xt[(wc + 2) * 520 + ic] = (_Float16)(v.z * s);
      Xt[(wc + 3) * 520 + ic] = (_Float16)(v.w * s);
    }
    __syncthreads();
    _Float16* xb = xsp + (size_t)b * 16 * 36992;
    const int r = h + 1;
    half8 z = {};
    for (int it = 0; it < 9; ++it) {     // 16 icb * 4 kkq * 34 C = 2176 chunks
      int c = it * 256 + tid;
      if (c < 2176) {
        int icb = c / 136, rem = c - 136 * icb, kkq = rem / 34, C = rem - 34 * kkq;
        half8 val = z;
        if (C != 0 && C != 33)
          val = *(const half8*)&Xt[(C - 1) * 520 + icb * 32 + kkq * 8];
        *(half8*)&xb[(size_t)icb * 36992 + (size_t)r * 1088 + kkq * 272 + C * 8] = val;
      }
    }
    if (h == 0 || h == 31) {             // zero top/bottom padded rows
      const int rz = (h == 0) ? 0 : 33;
      for (int it = 0; it < 9; ++it) {
        int c = it * 256 + tid;
        if (c < 2176) {
          int icb = c / 136, rem = c - 136 * icb, kkq = rem / 34, C = rem - 34 * kkq;
          *(half8*)&xb[(size_t)icb * 36992 + (size_t)rz * 1088 + kkq * 272 + C * 8] = z;
        }
      }
    }
  }
}

// ---- conv: block 32oc x 256px (8 rows), grid (x 16, bx 4, b 8) = 512 ----
// blockIdx.x = byq + 8*hoc; XCD = linear%8 = byq (weight slice locality).
// 4 waves/block, wave w owns output rows h0+2w, h0+2w+1 (two 32x32 tiles,
// acc[2]x16): 18 MFMA per sub-step from 9 A + 12 X ds_reads (s/kh reuse).
// 32 sub-steps (icb x kk); per stage A-quarter (9216 B) + X 10 rows
// (10880 B) via global_load_lds, double-buffered (LDS ~41.4 KB, 2 bl/CU).
// Staging = 20 wave-uniform 64-chunk groups, exactly 5 PER WAVE:
// w0 A0-4, w1 A5-8+X0, w2 X1-5, w3 X6-10(last 40 lanes) -> vmcnt(5).
__global__ __launch_bounds__(256, 2) void conv_kernel(
    const _Float16* __restrict__ Wtf,   // [8 byq][16 icb][36 m][64 oc][8]
    const _Float16* __restrict__ xsp,   // [8 b][16 icb][34 r][2 kk][2 kq][34 C][8]
    const float* __restrict__ dpart,    // [16 icb][8 b][512 oc]
    float* __restrict__ out) {          // [8][512][32][32]
  const int byq = blockIdx.x & 7, hoc = blockIdx.x >> 3;
  const int bx = blockIdx.y, b = blockIdx.z;
  const int tid = threadIdx.x, lane = tid & 63, w = tid >> 6;
  const int n = lane & 31, kq = lane >> 5;
  const int h0 = bx * 8;                // output rows h0..h0+7; padded h0..h0+9

  __shared__ __align__(16) _Float16 As[2][4608];   //  9216 B each (18r x 256)
  __shared__ __align__(16) _Float16 Xs[2][5440];   // 10880 B each (10r x 544)
  __shared__ float redd[8][32];
  __shared__ float dvl[32];

  const _Float16* gX = xsp + (size_t)b * 16 * 36992 + (size_t)h0 * 1088;
  const _Float16* gA = Wtf + (size_t)byq * 16 * 18432 + hoc * 256;

  // A chunks c in [0,576): r=c>>5 (0..17), o2=c&31;
  //   src halfs = icb*18432 + ((r>>1)*4 + kk*2 + (r&1))*512 + hoc*256 + o2*8
  // X chunks c in [0,680): r=c/68 (0..9), o=c%68;
  //   src halfs = icb*36992 + kk*544 + r*1088 + o*8
  auto stage = [&](int st, int p) {
    const int icb = st >> 1, kk = st & 1;
    const _Float16* a = gA + (size_t)icb * 18432 + kk * 1024;
    const _Float16* xg = gX + (size_t)icb * 36992 + kk * 544;
    if (w == 0) {
#pragma unroll
      for (int k = 0; k < 5; ++k) {      // A groups 0-4
        int c = k * 64 + lane;
        int r = c >> 5, o2 = c & 31;
        g2l(a + ((r >> 1) * 4 + (r & 1)) * 512 + o2 * 8, &As[p][c * 8]);
      }
    } else if (w == 1) {
#pragma unroll
      for (int k = 0; k < 4; ++k) {      // A groups 5-8
        int c = (5 + k) * 64 + lane;
        int r = c >> 5, o2 = c & 31;
        g2l(a + ((r >> 1) * 4 + (r & 1)) * 512 + o2 * 8, &As[p][c * 8]);
      }
      {                                  // X group 0
        int c = lane, r = c / 68, o = c - r * 68;
        g2l(xg + r * 1088 + o * 8, &Xs[p][c * 8]);
      }
    } else if (w == 2) {
#pragma unroll
      for (int k = 0; k < 5; ++k) {      // X groups 1-5
        int c = (1 + k) * 64 + lane;
        int r = c / 68, o = c - r * 68;
        g2l(xg + r * 1088 + o * 8, &Xs[p][c * 8]);
      }
    } else {
#pragma unroll
      for (int k = 0; k < 4; ++k) {      // X groups 6-9
        int c = (6 + k) * 64 + lane;
        int r = c / 68, o = c - r * 68;
        g2l(xg + r * 1088 + o * 8, &Xs[p][c * 8]);
      }
      {                                  // X group 10 (partial: 40 lanes)
        int c = 640 + lane;
        if (lane < 40) {
          int r = c / 68, o = c - r * 68;
          g2l(xg + r * 1088 + o * 8, &Xs[p][c * 8]);
        }
      }
    }
  };

  floatx16 acc[2] = {};
  stage(0, 0);                           // prologue: 5 g2l in flight
  for (int st = 0; st < 32; ++st) {
    const int cur = st & 1;
    if (st + 1 < 32) {
      stage(st + 1, cur ^ 1);            // issue next (5 g2l) -> 10 in flight
      asm volatile("s_waitcnt vmcnt(5)" ::: "memory");  // my buf[cur] done
    } else {
      asm volatile("s_waitcnt vmcnt(0)" ::: "memory");
    }
    __builtin_amdgcn_s_barrier();        // all waves' buf[cur] writes done
    __builtin_amdgcn_sched_barrier(0);   // pin: no ds_read hoists above
    const _Float16* Ap = &As[cur][0] + kq * 256 + n * 8;
    const _Float16* Xp = &Xs[cur][0] + (2 * w) * 544 + kq * 272 + n * 8;
    half8 a[9];
#pragma unroll
    for (int t = 0; t < 9; ++t) a[t] = *(const half8*)(Ap + t * 512);
    __builtin_amdgcn_s_setprio(1);
#pragma unroll
    for (int s = 0; s < 4; ++s) {        // staged row 2w+s; out rows j=0,1
#pragma unroll
      for (int kw = 0; kw < 3; ++kw) {
        half8 xv = *(const half8*)(Xp + s * 544 + kw * 8);
#pragma unroll
        for (int kh = 0; kh < 3; ++kh) {
          int j = s - kh;
          if (j >= 0 && j < 2)
            acc[j] = __builtin_amdgcn_mfma_f32_32x32x16_f16(
                a[kh * 3 + kw], xv, acc[j], 0, 0, 0);
        }
      }
    }
    __builtin_amdgcn_s_setprio(0);
    __builtin_amdgcn_sched_barrier(0);   // pin: no ds_read sinks below
    __builtin_amdgcn_s_barrier();        // buf[cur^1] reads done (WAR)
  }

  // epilogue: reduce dpart over 16 icb -> dvl[32], then plain stores
  const int oc0 = byq * 64 + hoc * 32;
  __syncthreads();
  {
    const int oc_l = tid & 31, ig = tid >> 5;
    float s = dpart[(size_t)(ig * 2) * 4096 + b * OC_ + oc0 + oc_l] +
              dpart[(size_t)(ig * 2 + 1) * 4096 + b * OC_ + oc0 + oc_l];
    redd[ig][oc_l] = s;
  }
  __syncthreads();
  if (tid < 32) {
    float s = 1e-8f;
#pragma unroll
    for (int g = 0; g < 8; ++g) s += redd[g][tid];
    dvl[tid] = rsqrtf(s);
  }
  __syncthreads();
  // D col(px)=n, row(oc within 32)=(rg&3)+8*(rg>>2)+4*kq
  const int r0 = h0 + 2 * w;
#pragma unroll
  for (int rg = 0; rg < 16; ++rg) {
    const int row = (rg & 3) + 8 * (rg >> 2) + 4 * kq;
    const float dv = dvl[row];
    float* op = out + ((size_t)b * OC_ + oc0 + row) * 1024 + r0 * 32 + n;
    op[0]  = acc[0][rg] * dv;
    op[32] = acc[1][rg] * dv;
  }
}

extern "C" void kernel_launch(void* const* d_in, const int* in_sizes, int n_in,
                              void* d_out, int out_size, void* d_ws, size_t ws_size,
                              hipStream_t stream) {
  const float* x       = (const float*)d_in[0];
  const float* w       = (const float*)d_in[1];
  const float* conv_w  = (const float*)d_in[2];
  const float* dense_w = (const float*)d_in[3];
  const float* dense_b = (const float*)d_in[4];
  float* out = (float*)d_out;

  char* ws = (char*)d_ws;
  float*    sm    = (float*)ws;                        // 16 KB
  float*    sm2   = (float*)(ws + (16 << 10));         // 16 KB
  float*    dpart = (float*)(ws + (32 << 10));         // 256 KB
  _Float16* Wtf   = (_Float16*)(ws + (288 << 10));               // 4,718,592 B
  _Float16* xsp   = (_Float16*)(ws + (288 << 10) + 4718592);     // 9,469,952 B

  style_kernel<<<dim3(8, B_), 256, 0, stream>>>(w, dense_w, dense_b, sm, sm2);
  prep_kernel<<<512, 256, 0, stream>>>(conv_w, x, sm, sm2, Wtf, dpart, xsp);
  conv_kernel<<<dim3(16, 4, B_), 256, 0, stream>>>(Wtf, xsp, dpart, out);
}